// Round 2
// baseline (3207.273 us; speedup 1.0000x reference)
//
#include <hip/hip_runtime.h>

typedef unsigned short u16;
typedef unsigned int u32;

#define B_   16
#define C_   384
#define H_   28
#define W_   28
#define S_   784
#define NH_  6
#define HD_  64
#define BS_  (B_ * S_)            // 12544
#define SCALE_ 0.05103103630798288f  // 384^-0.5
#define EPS_ 1e-5f

__device__ __forceinline__ float bf2f(u16 u) {
    return __uint_as_float(((u32)u) << 16);
}
__device__ __forceinline__ float bflo(u32 u) { return __uint_as_float(u << 16); }
__device__ __forceinline__ float bfhi(u32 u) { return __uint_as_float(u & 0xffff0000u); }
__device__ __forceinline__ u16 f2bf(float f) {
    u32 x = __float_as_uint(f);
    u32 r = (x + 0x7fffu + ((x >> 16) & 1u)) >> 16;   // RNE
    return (u16)r;
}
__device__ __forceinline__ u32 pack2(float a, float b) {
    return (u32)f2bf(a) | ((u32)f2bf(b) << 16);
}

// ---------------------------------------------------------------------------
// Kernel 1: build img[3][B][C][S] (bf16) from f32 x1,x2 (b,s,c) via LDS
// transpose. img0 = x1^T, img1 = x2^T, img2 = (x1+x2)^T
// ---------------------------------------------------------------------------
__global__ void k_img(const float* __restrict__ x1, const float* __restrict__ x2,
                      u16* __restrict__ img) {
    __shared__ float sm[32][33];
    int i = blockIdx.z >> 4;        // image 0..2
    int b = blockIdx.z & 15;
    int s0 = blockIdx.x * 32;
    int c0 = blockIdx.y * 32;
    int tx = threadIdx.x;           // 0..31
    int ty = threadIdx.y;           // 0..7
#pragma unroll
    for (int r = 0; r < 4; ++r) {
        int s = s0 + ty + 8 * r;
        int c = c0 + tx;
        float v = 0.f;
        if (s < S_) {
            int off = (b * S_ + s) * C_ + c;
            if (i == 0)       v = x1[off];
            else if (i == 1)  v = x2[off];
            else              v = x1[off] + x2[off];
        }
        sm[ty + 8 * r][tx] = v;
    }
    __syncthreads();
#pragma unroll
    for (int r = 0; r < 4; ++r) {
        int c = c0 + ty + 8 * r;
        int s = s0 + tx;
        if (s < S_)
            img[((i * B_ + b) * C_ + c) * S_ + s] = f2bf(sm[tx][ty + 8 * r]);
    }
}

// ---------------------------------------------------------------------------
// Kernel 2: depthwise 3x3 conv (pad 1). y[idx][b][c][s] bf16, idx=0..8.
// branch = idx/3 selects img plane. dw weights are f32.
// ---------------------------------------------------------------------------
__global__ void k_conv(const u16* __restrict__ img, const float* __restrict__ dw,
                       u16* __restrict__ y) {
    __shared__ float plane[S_];
    int c = blockIdx.x, b = blockIdx.y, idx = blockIdx.z;
    int br = idx / 3;
    const u16* src = img + ((br * B_ + b) * C_ + c) * S_;
    int tid = threadIdx.x;
    for (int e = tid; e < S_; e += 256) plane[e] = bf2f(src[e]);
    float wt[9];
#pragma unroll
    for (int k = 0; k < 9; ++k) wt[k] = dw[(idx * C_ + c) * 9 + k];
    __syncthreads();
    u16* dst = y + ((idx * B_ + b) * C_ + c) * S_;
    for (int px = tid; px < S_; px += 256) {
        int h = px / W_, w = px % W_;
        float acc = 0.f;
#pragma unroll
        for (int kh = 0; kh < 3; ++kh) {
            int ih = h + kh - 1;
            if (ih < 0 || ih >= H_) continue;
#pragma unroll
            for (int kw = 0; kw < 3; ++kw) {
                int iw = w + kw - 1;
                if (iw < 0 || iw >= W_) continue;
                acc += plane[ih * W_ + iw] * wt[kh * 3 + kw];
            }
        }
        dst[px] = f2bf(acc);
    }
}

// ---------------------------------------------------------------------------
// Kernel 3: BN batch stats per (idx, c) over (b,s). Outputs folded affine:
// aScale = gamma * rsqrt(var+eps); bShift = beta - mean*aScale.
// ---------------------------------------------------------------------------
__global__ void k_stats(const u16* __restrict__ y, const float* __restrict__ gamma,
                        const float* __restrict__ beta,
                        float* __restrict__ aScale, float* __restrict__ bShift) {
    __shared__ float rs[256], rq[256];
    int c = blockIdx.x, idx = blockIdx.y;
    int tid = threadIdx.x;
    float s = 0.f, q = 0.f;
    for (int b = 0; b < B_; ++b) {
        const u16* p = y + ((idx * B_ + b) * C_ + c) * S_;
        for (int e = tid; e < S_; e += 256) {
            float v = bf2f(p[e]);
            s += v; q += v * v;
        }
    }
    rs[tid] = s; rq[tid] = q;
    __syncthreads();
    for (int st = 128; st > 0; st >>= 1) {
        if (tid < st) { rs[tid] += rs[tid + st]; rq[tid] += rq[tid + st]; }
        __syncthreads();
    }
    if (tid == 0) {
        float mean = rs[0] / (float)BS_;
        float var  = rq[0] / (float)BS_ - mean * mean;
        float a = gamma[idx * C_ + c] * rsqrtf(var + EPS_);
        aScale[idx * C_ + c] = a;
        bShift[idx * C_ + c] = beta[idx * C_ + c] - mean * a;
    }
}

// ---------------------------------------------------------------------------
// Kernel 4: combined weights (all-f32 math).
// W1[o,c] = sum_m lin[li][o][m]*pw[idx][m][c]
// Wc[idx][o][c] = W1*aScale[c]  (f32)
// Bc[idx][o] = sum_c bShift[c]*W1[o,c] + sum_m lin[li][o][m]*pwb[idx][m]
// block = (idx, og): 384 threads (c), 8 o's per block.
// ---------------------------------------------------------------------------
__global__ void k_wcomb(const float* __restrict__ pw, const float* __restrict__ pwb,
                        const float* __restrict__ lin,
                        const float* __restrict__ aScale, const float* __restrict__ bShift,
                        float* __restrict__ Wc, float* __restrict__ Bc) {
    __shared__ float red[C_];
    int og = blockIdx.x;            // 0..47
    int idx = blockIdx.y;           // 0..8
    int c = threadIdx.x;            // 0..383
    int li = (idx < 3) ? idx : 3 + (idx % 3);   // replicate branch-2 lin reuse bug
    float acc[8];
#pragma unroll
    for (int k = 0; k < 8; ++k) acc[k] = 0.f;
    const float* pwm = pw + (idx * C_) * C_ + c;          // pw[idx][m][c]
    const float* lb  = lin + ((li * C_) + og * 8) * C_;   // lin[li][og*8+k][m]
    for (int m = 0; m < C_; ++m) {
        float pv = pwm[m * C_];
#pragma unroll
        for (int k = 0; k < 8; ++k)
            acc[k] += lb[k * C_ + m] * pv;
    }
    float aS = aScale[idx * C_ + c];
    float bS = bShift[idx * C_ + c];
    float pwbc = pwb[idx * C_ + c];
    for (int k = 0; k < 8; ++k) {
        int o = og * 8 + k;
        Wc[(idx * C_ + o) * C_ + c] = acc[k] * aS;
        float part = acc[k] * bS + lin[(li * C_ + o) * C_ + c] * pwbc;
        red[c] = part;
        __syncthreads();
        if (c < 128) red[c] += red[c + 256];
        __syncthreads();
        if (c < 128) red[c] += red[c + 128];
        __syncthreads();
        for (int st = 64; st > 0; st >>= 1) {
            if (c < st) red[c] += red[c + st];
            __syncthreads();
        }
        if (c == 0) Bc[idx * C_ + o] = red[0];
        __syncthreads();
    }
}

// ---------------------------------------------------------------------------
// Kernel 5: GEMM per (idx,b): qkv[idx][b][s][o] = sum_c y[idx][b][c][s]*Wc[idx][o][c] + Bc[o]
// A is K-major (c,s) bf16; B is (o,c) f32. 64x64 tile, 4x4 per thread, K-tile 16.
// ---------------------------------------------------------------------------
__launch_bounds__(256)
__global__ void k_gemm(const u16* __restrict__ y, const float* __restrict__ Wc,
                       const float* __restrict__ Bc, u16* __restrict__ qkv) {
    __shared__ float As[16][68];
    __shared__ float Bs[16][68];
    int idx = blockIdx.z >> 4;
    int b   = blockIdx.z & 15;
    int s0 = blockIdx.x * 64;
    int o0 = blockIdx.y * 64;
    int tid = threadIdx.x;
    int ty = tid >> 4, tx = tid & 15;
    float acc[4][4];
#pragma unroll
    for (int i = 0; i < 4; ++i)
#pragma unroll
        for (int j = 0; j < 4; ++j) acc[i][j] = 0.f;

    const u16* Abase = y + ((idx * B_ + b) * C_) * S_;
    const float* Bbase = Wc + (idx * C_ + o0) * C_;
    int lakk = tid >> 4;            // 0..15
    int las  = (tid & 15) * 4;      // 0..60
    int lbo  = tid >> 2;            // 0..63
    int lbk  = (tid & 3) * 4;       // 0,4,8,12

    for (int k0 = 0; k0 < C_; k0 += 16) {
        float a0 = 0.f, a1 = 0.f, a2 = 0.f, a3 = 0.f;
        int scol = s0 + las;
        if (scol < S_) {
            const u16* p = Abase + (k0 + lakk) * S_ + scol;
            u32 lo = *(const u32*)p;
            u32 hi = *(const u32*)(p + 2);
            a0 = bflo(lo); a1 = bfhi(lo); a2 = bflo(hi); a3 = bfhi(hi);
        }
        As[lakk][las + 0] = a0; As[lakk][las + 1] = a1;
        As[lakk][las + 2] = a2; As[lakk][las + 3] = a3;

        float4 bv = *(const float4*)(Bbase + lbo * C_ + k0 + lbk);
        Bs[lbk + 0][lbo] = bv.x; Bs[lbk + 1][lbo] = bv.y;
        Bs[lbk + 2][lbo] = bv.z; Bs[lbk + 3][lbo] = bv.w;
        __syncthreads();
#pragma unroll
        for (int kk = 0; kk < 16; ++kk) {
            float av[4], bw[4];
#pragma unroll
            for (int i = 0; i < 4; ++i) av[i] = As[kk][ty * 4 + i];
#pragma unroll
            for (int j = 0; j < 4; ++j) bw[j] = Bs[kk][tx * 4 + j];
#pragma unroll
            for (int i = 0; i < 4; ++i)
#pragma unroll
                for (int j = 0; j < 4; ++j) acc[i][j] += av[i] * bw[j];
        }
        __syncthreads();
    }
    // epilogue
    float bias[4];
#pragma unroll
    for (int j = 0; j < 4; ++j) bias[j] = Bc[idx * C_ + o0 + tx * 4 + j];
    u16* out = qkv + ((idx * B_ + b) * S_) * C_;
#pragma unroll
    for (int i = 0; i < 4; ++i) {
        int s = s0 + ty * 4 + i;
        if (s >= S_) continue;
        uint2 w;
        w.x = pack2(acc[i][0] + bias[0], acc[i][1] + bias[1]);
        w.y = pack2(acc[i][2] + bias[2], acc[i][3] + bias[3]);
        *(uint2*)(out + s * C_ + o0 + tx * 4) = w;
    }
}

// ---------------------------------------------------------------------------
// Kernel 6: attention. 1 thread per Q-row, online softmax, K/V chunks in LDS.
// out flat layout replicates torch .view(b,t,h*d) on (b,h,t,d):
//   out[br][b][h][t][d] contiguous. Output is f32.
// ---------------------------------------------------------------------------
__launch_bounds__(256, 2)
__global__ void k_attn(const u16* __restrict__ qkv, float* __restrict__ out) {
    __shared__ float Ks[64][64];
    __shared__ float Vs[64][64];
    int h = blockIdx.y;
    int z = blockIdx.z;
    int br = z >> 4, b = z & 15;
    int tid = threadIdx.x;
    int r = blockIdx.x * 256 + tid;
    int idxq = 3 * br;
    const u16* qp = qkv + ((idxq * B_ + b) * S_) * C_ + h * HD_;
    const u16* kp = qkv + (((idxq + 1) * B_ + b) * S_) * C_ + h * HD_;
    const u16* vp = qkv + (((idxq + 2) * B_ + b) * S_) * C_ + h * HD_;

    bool act = (r < S_);
    float q[64];
    if (act) {
        const uint4* p = reinterpret_cast<const uint4*>(qp + (size_t)r * C_);
#pragma unroll
        for (int i = 0; i < 8; ++i) {
            uint4 u = p[i];
            q[i * 8 + 0] = bflo(u.x); q[i * 8 + 1] = bfhi(u.x);
            q[i * 8 + 2] = bflo(u.y); q[i * 8 + 3] = bfhi(u.y);
            q[i * 8 + 4] = bflo(u.z); q[i * 8 + 5] = bfhi(u.z);
            q[i * 8 + 6] = bflo(u.w); q[i * 8 + 7] = bfhi(u.w);
        }
    } else {
#pragma unroll
        for (int d = 0; d < 64; ++d) q[d] = 0.f;
    }
    float oacc[64];
#pragma unroll
    for (int d = 0; d < 64; ++d) oacc[d] = 0.f;
    float m = -INFINITY, l = 0.f;

    int ltl = tid >> 2;             // 0..63
    int ldq = (tid & 3) * 16;       // 0,16,32,48

    for (int tc = 0; tc < S_; tc += 64) {
        int tg = tc + ltl;
        if (tg < S_) {
            const uint4* pk4 = reinterpret_cast<const uint4*>(kp + (size_t)tg * C_ + ldq);
            const uint4* pv4 = reinterpret_cast<const uint4*>(vp + (size_t)tg * C_ + ldq);
#pragma unroll
            for (int i = 0; i < 2; ++i) {
                uint4 u = pk4[i];
                float* kd = &Ks[ltl][ldq + i * 8];
                kd[0] = bflo(u.x); kd[1] = bfhi(u.x);
                kd[2] = bflo(u.y); kd[3] = bfhi(u.y);
                kd[4] = bflo(u.z); kd[5] = bfhi(u.z);
                kd[6] = bflo(u.w); kd[7] = bfhi(u.w);
                uint4 w = pv4[i];
                float* vd = &Vs[ltl][ldq + i * 8];
                vd[0] = bflo(w.x); vd[1] = bfhi(w.x);
                vd[2] = bflo(w.y); vd[3] = bfhi(w.y);
                vd[4] = bflo(w.z); vd[5] = bfhi(w.z);
                vd[6] = bflo(w.w); vd[7] = bfhi(w.w);
            }
        }
        __syncthreads();
        if (act) {
            int tmax = min(64, S_ - tc);
            for (int tt = 0; tt < tmax; ++tt) {
                float d0 = 0.f, d1 = 0.f, d2 = 0.f, d3 = 0.f;
#pragma unroll
                for (int d4 = 0; d4 < 64; d4 += 4) {
                    d0 += q[d4 + 0] * Ks[tt][d4 + 0];
                    d1 += q[d4 + 1] * Ks[tt][d4 + 1];
                    d2 += q[d4 + 2] * Ks[tt][d4 + 2];
                    d3 += q[d4 + 3] * Ks[tt][d4 + 3];
                }
                float logit = ((d0 + d1) + (d2 + d3)) * SCALE_;
                float mnew = fmaxf(m, logit);
                float alpha = __expf(m - mnew);
                float p = __expf(logit - mnew);
                l = l * alpha + p;
#pragma unroll
                for (int d = 0; d < 64; ++d)
                    oacc[d] = oacc[d] * alpha + p * Vs[tt][d];
                m = mnew;
            }
        }
        __syncthreads();
    }
    if (act) {
        float inv = 1.f / l;
        float* op = out + (((size_t)(br * B_ + b) * NH_ + h) * S_ + r) * HD_;
        float4* op4 = reinterpret_cast<float4*>(op);
#pragma unroll
        for (int i = 0; i < 16; ++i) {
            float4 u;
            u.x = oacc[i * 4 + 0] * inv;
            u.y = oacc[i * 4 + 1] * inv;
            u.z = oacc[i * 4 + 2] * inv;
            u.w = oacc[i * 4 + 3] * inv;
            op4[i] = u;
        }
    }
}

// ---------------------------------------------------------------------------
extern "C" void kernel_launch(void* const* d_in, const int* in_sizes, int n_in,
                              void* d_out, int out_size, void* d_ws, size_t ws_size,
                              hipStream_t stream) {
    (void)in_sizes; (void)n_in; (void)out_size; (void)ws_size;
    const float* x1    = (const float*)d_in[0];
    const float* x2    = (const float*)d_in[3];
    const float* dw    = (const float*)d_in[6];
    const float* gamma = (const float*)d_in[7];
    const float* beta  = (const float*)d_in[8];
    const float* pw    = (const float*)d_in[9];
    const float* pwb   = (const float*)d_in[10];
    const float* lin   = (const float*)d_in[11];
    float* out = (float*)d_out;

    char* ws = (char*)d_ws;
    // ws layout (bytes):
    // img  bf16 [3][16][384][784]  @ 0          size 28,901,376
    // y    bf16 [9][16][384][784]  @ 28901376   size 86,704,128
    // qkv  bf16 [9][16][784][384]  @ 115605504  size 86,704,128
    // Wc   f32  [9][384][384]      @ 202309632  size 5,308,416
    // Bc   f32  [9][384]           @ 207618048  size 13,824
    // aS   f32  [9][384]           @ 207631872  size 13,824
    // bS   f32  [9][384]           @ 207645696  size 13,824
    u16*  img = (u16*)(ws);
    u16*  y   = (u16*)(ws + 28901376);
    u16*  qkv = (u16*)(ws + 115605504);
    float* Wc = (float*)(ws + 202309632);
    float* Bc = (float*)(ws + 207618048);
    float* aS = (float*)(ws + 207631872);
    float* bS = (float*)(ws + 207645696);

    k_img  <<<dim3(25, 12, 48), dim3(32, 8), 0, stream>>>(x1, x2, img);
    k_conv <<<dim3(384, 16, 9), 256, 0, stream>>>(img, dw, y);
    k_stats<<<dim3(384, 9), 256, 0, stream>>>(y, gamma, beta, aS, bS);
    k_wcomb<<<dim3(48, 9), 384, 0, stream>>>(pw, pwb, lin, aS, bS, Wc, Bc);
    k_gemm <<<dim3(13, 6, 144), 256, 0, stream>>>(y, Wc, Bc, qkv);
    k_attn <<<dim3(4, 6, 48), 256, 0, stream>>>(qkv, out);
}

// Round 3
// 991.957 us; speedup vs baseline: 3.2333x; 3.2333x over previous
//
#include <hip/hip_runtime.h>

typedef unsigned short u16;
typedef unsigned int u32;
typedef unsigned long long u64;

#define B_   16
#define C_   384
#define H_   28
#define W_   28
#define S_   784
#define NH_  6
#define HD_  64
#define BS_  (B_ * S_)            // 12544
#define SCALE_ 0.05103103630798288f  // 384^-0.5
#define EPS_ 1e-5f

typedef __attribute__((ext_vector_type(8))) short bf16x8;
typedef __attribute__((ext_vector_type(4))) float f32x4;

__device__ __forceinline__ float bf2f(u16 u) {
    return __uint_as_float(((u32)u) << 16);
}
__device__ __forceinline__ float bflo(u32 u) { return __uint_as_float(u << 16); }
__device__ __forceinline__ float bfhi(u32 u) { return __uint_as_float(u & 0xffff0000u); }
__device__ __forceinline__ u16 f2bf(float f) {
    u32 x = __float_as_uint(f);
    u32 r = (x + 0x7fffu + ((x >> 16) & 1u)) >> 16;   // RNE
    return (u16)r;
}
__device__ __forceinline__ u32 pack2(float a, float b) {
    return (u32)f2bf(a) | ((u32)f2bf(b) << 16);
}

// ---------------------------------------------------------------------------
// Kernel 1: build img[3][B][C][S] (bf16) from f32 x1,x2 (b,s,c) via LDS
// transpose. img0 = x1^T, img1 = x2^T, img2 = (x1+x2)^T
// ---------------------------------------------------------------------------
__global__ void k_img(const float* __restrict__ x1, const float* __restrict__ x2,
                      u16* __restrict__ img) {
    __shared__ float sm[32][33];
    int i = blockIdx.z >> 4;        // image 0..2
    int b = blockIdx.z & 15;
    int s0 = blockIdx.x * 32;
    int c0 = blockIdx.y * 32;
    int tx = threadIdx.x;           // 0..31
    int ty = threadIdx.y;           // 0..7
#pragma unroll
    for (int r = 0; r < 4; ++r) {
        int s = s0 + ty + 8 * r;
        int c = c0 + tx;
        float v = 0.f;
        if (s < S_) {
            int off = (b * S_ + s) * C_ + c;
            if (i == 0)       v = x1[off];
            else if (i == 1)  v = x2[off];
            else              v = x1[off] + x2[off];
        }
        sm[ty + 8 * r][tx] = v;
    }
    __syncthreads();
#pragma unroll
    for (int r = 0; r < 4; ++r) {
        int c = c0 + ty + 8 * r;
        int s = s0 + tx;
        if (s < S_)
            img[((i * B_ + b) * C_ + c) * S_ + s] = f2bf(sm[tx][ty + 8 * r]);
    }
}

// ---------------------------------------------------------------------------
// Kernel 2: depthwise 3x3 conv (pad 1). y[idx][b][c][s] bf16, idx=0..8.
// ---------------------------------------------------------------------------
__global__ void k_conv(const u16* __restrict__ img, const float* __restrict__ dw,
                       u16* __restrict__ y) {
    __shared__ float plane[S_];
    int c = blockIdx.x, b = blockIdx.y, idx = blockIdx.z;
    int br = idx / 3;
    const u16* src = img + ((br * B_ + b) * C_ + c) * S_;
    int tid = threadIdx.x;
    for (int e = tid; e < S_; e += 256) plane[e] = bf2f(src[e]);
    float wt[9];
#pragma unroll
    for (int k = 0; k < 9; ++k) wt[k] = dw[(idx * C_ + c) * 9 + k];
    __syncthreads();
    u16* dst = y + ((idx * B_ + b) * C_ + c) * S_;
    for (int px = tid; px < S_; px += 256) {
        int h = px / W_, w = px % W_;
        float acc = 0.f;
#pragma unroll
        for (int kh = 0; kh < 3; ++kh) {
            int ih = h + kh - 1;
            if (ih < 0 || ih >= H_) continue;
#pragma unroll
            for (int kw = 0; kw < 3; ++kw) {
                int iw = w + kw - 1;
                if (iw < 0 || iw >= W_) continue;
                acc += plane[ih * W_ + iw] * wt[kh * 3 + kw];
            }
        }
        dst[px] = f2bf(acc);
    }
}

// ---------------------------------------------------------------------------
// Kernel 3: BN batch stats per (idx, c). Folded affine out.
// ---------------------------------------------------------------------------
__global__ void k_stats(const u16* __restrict__ y, const float* __restrict__ gamma,
                        const float* __restrict__ beta,
                        float* __restrict__ aScale, float* __restrict__ bShift) {
    __shared__ float rs[256], rq[256];
    int c = blockIdx.x, idx = blockIdx.y;
    int tid = threadIdx.x;
    float s = 0.f, q = 0.f;
    for (int b = 0; b < B_; ++b) {
        const u16* p = y + ((idx * B_ + b) * C_ + c) * S_;
        for (int e = tid; e < S_; e += 256) {
            float v = bf2f(p[e]);
            s += v; q += v * v;
        }
    }
    rs[tid] = s; rq[tid] = q;
    __syncthreads();
    for (int st = 128; st > 0; st >>= 1) {
        if (tid < st) { rs[tid] += rs[tid + st]; rq[tid] += rq[tid + st]; }
        __syncthreads();
    }
    if (tid == 0) {
        float mean = rs[0] / (float)BS_;
        float var  = rq[0] / (float)BS_ - mean * mean;
        float a = gamma[idx * C_ + c] * rsqrtf(var + EPS_);
        aScale[idx * C_ + c] = a;
        bShift[idx * C_ + c] = beta[idx * C_ + c] - mean * a;
    }
}

// ---------------------------------------------------------------------------
// Kernel 4: combined weights (all-f32 math).
// ---------------------------------------------------------------------------
__global__ void k_wcomb(const float* __restrict__ pw, const float* __restrict__ pwb,
                        const float* __restrict__ lin,
                        const float* __restrict__ aScale, const float* __restrict__ bShift,
                        float* __restrict__ Wc, float* __restrict__ Bc) {
    __shared__ float red[C_];
    int og = blockIdx.x;            // 0..47
    int idx = blockIdx.y;           // 0..8
    int c = threadIdx.x;            // 0..383
    int li = (idx < 3) ? idx : 3 + (idx % 3);   // replicate branch-2 lin reuse bug
    float acc[8];
#pragma unroll
    for (int k = 0; k < 8; ++k) acc[k] = 0.f;
    const float* pwm = pw + (idx * C_) * C_ + c;
    const float* lb  = lin + ((li * C_) + og * 8) * C_;
    for (int m = 0; m < C_; ++m) {
        float pv = pwm[m * C_];
#pragma unroll
        for (int k = 0; k < 8; ++k)
            acc[k] += lb[k * C_ + m] * pv;
    }
    float aS = aScale[idx * C_ + c];
    float bS = bShift[idx * C_ + c];
    float pwbc = pwb[idx * C_ + c];
    for (int k = 0; k < 8; ++k) {
        int o = og * 8 + k;
        Wc[(idx * C_ + o) * C_ + c] = acc[k] * aS;
        float part = acc[k] * bS + lin[(li * C_ + o) * C_ + c] * pwbc;
        red[c] = part;
        __syncthreads();
        if (c < 128) red[c] += red[c + 256];
        __syncthreads();
        if (c < 128) red[c] += red[c + 128];
        __syncthreads();
        for (int st = 64; st > 0; st >>= 1) {
            if (c < st) red[c] += red[c + st];
            __syncthreads();
        }
        if (c == 0) Bc[idx * C_ + o] = red[0];
        __syncthreads();
    }
}

// ---------------------------------------------------------------------------
// Kernel 5: GEMM per (idx,b) (unchanged, f32 VALU; MFMA next round).
// ---------------------------------------------------------------------------
__launch_bounds__(256)
__global__ void k_gemm(const u16* __restrict__ y, const float* __restrict__ Wc,
                       const float* __restrict__ Bc, u16* __restrict__ qkv) {
    __shared__ float As[16][68];
    __shared__ float Bs[16][68];
    int idx = blockIdx.z >> 4;
    int b   = blockIdx.z & 15;
    int s0 = blockIdx.x * 64;
    int o0 = blockIdx.y * 64;
    int tid = threadIdx.x;
    int ty = tid >> 4, tx = tid & 15;
    float acc[4][4];
#pragma unroll
    for (int i = 0; i < 4; ++i)
#pragma unroll
        for (int j = 0; j < 4; ++j) acc[i][j] = 0.f;

    const u16* Abase = y + ((idx * B_ + b) * C_) * S_;
    const float* Bbase = Wc + (idx * C_ + o0) * C_;
    int lakk = tid >> 4;
    int las  = (tid & 15) * 4;
    int lbo  = tid >> 2;
    int lbk  = (tid & 3) * 4;

    for (int k0 = 0; k0 < C_; k0 += 16) {
        float a0 = 0.f, a1 = 0.f, a2 = 0.f, a3 = 0.f;
        int scol = s0 + las;
        if (scol < S_) {
            const u16* p = Abase + (k0 + lakk) * S_ + scol;
            u32 lo = *(const u32*)p;
            u32 hi = *(const u32*)(p + 2);
            a0 = bflo(lo); a1 = bfhi(lo); a2 = bflo(hi); a3 = bfhi(hi);
        }
        As[lakk][las + 0] = a0; As[lakk][las + 1] = a1;
        As[lakk][las + 2] = a2; As[lakk][las + 3] = a3;

        float4 bv = *(const float4*)(Bbase + lbo * C_ + k0 + lbk);
        Bs[lbk + 0][lbo] = bv.x; Bs[lbk + 1][lbo] = bv.y;
        Bs[lbk + 2][lbo] = bv.z; Bs[lbk + 3][lbo] = bv.w;
        __syncthreads();
#pragma unroll
        for (int kk = 0; kk < 16; ++kk) {
            float av[4], bw[4];
#pragma unroll
            for (int i = 0; i < 4; ++i) av[i] = As[kk][ty * 4 + i];
#pragma unroll
            for (int j = 0; j < 4; ++j) bw[j] = Bs[kk][tx * 4 + j];
#pragma unroll
            for (int i = 0; i < 4; ++i)
#pragma unroll
                for (int j = 0; j < 4; ++j) acc[i][j] += av[i] * bw[j];
        }
        __syncthreads();
    }
    float bias[4];
#pragma unroll
    for (int j = 0; j < 4; ++j) bias[j] = Bc[idx * C_ + o0 + tx * 4 + j];
    u16* out = qkv + ((idx * B_ + b) * S_) * C_;
#pragma unroll
    for (int i = 0; i < 4; ++i) {
        int s = s0 + ty * 4 + i;
        if (s >= S_) continue;
        uint2 w;
        w.x = pack2(acc[i][0] + bias[0], acc[i][1] + bias[1]);
        w.y = pack2(acc[i][2] + bias[2], acc[i][3] + bias[3]);
        *(uint2*)(out + s * C_ + o0 + tx * 4) = w;
    }
}

// ---------------------------------------------------------------------------
// Kernel 6: MFMA flash attention.
// Block = 256 thr (4 waves) = one (br,b,h), 64 Q-rows (16 per wave).
// Loop T in 64-chunks: QK^T via mfma_16x16x32_bf16 (Q A-frags + K B-frags
// straight from global), online softmax in-register (shfl_xor row groups),
// P -> LDS (C-layout scatter) -> A-frags; V staged transposed [d][t] in LDS
// (double-buffered), PV accumulates O in C-frags.
// mfma layouts (verified, learn_hip m89/m91/m120):
//   A: lane holds A[m=lane&15][k=(lane>>4)*8+j]
//   B: lane holds B[k=(lane>>4)*8+j][n=lane&15]
//   C/D: lane holds D[row=(lane>>4)*4+reg][col=lane&15]
// ---------------------------------------------------------------------------
__launch_bounds__(256)
__global__ void k_attn(const u16* __restrict__ qkv, float* __restrict__ out) {
    // LDS (u16 units): V double-buffer 2*4352 (64 d-rows * 68), P 4*1088
    __shared__ u16 sm[13056];

    int h = blockIdx.y;
    int z = blockIdx.z;             // br*16 + b
    int br = z >> 4;
    int qtile = blockIdx.x;         // 0..12
    int tid = threadIdx.x;
    int wave = tid >> 6;
    int lane = tid & 63;
    int lq = lane & 15;             // n/m index
    int quad = lane >> 4;           // 0..3

    int idxq = 3 * br;
    const u16* qp = qkv + (size_t)((idxq * B_ + (z & 15)) * S_) * C_ + h * HD_;
    const u16* kp = qkv + (size_t)(((idxq + 1) * B_ + (z & 15)) * S_) * C_ + h * HD_;
    const u16* vp = qkv + (size_t)(((idxq + 2) * B_ + (z & 15)) * S_) * C_ + h * HD_;

    // ---- Q A-frags (2: d 0..31, 32..63), rows qbase + (lane&15), clamped
    int qbase = qtile * 64 + wave * 16;
    int qrow = qbase + lq; if (qrow > S_ - 1) qrow = S_ - 1;
    const u16* qptr = qp + (size_t)qrow * C_ + quad * 8;
    bf16x8 aq0 = *(const bf16x8*)qptr;
    bf16x8 aq1 = *(const bf16x8*)(qptr + 32);

    f32x4 o0 = {0.f,0.f,0.f,0.f}, o1 = o0, o2 = o0, o3 = o0;
    float mrow[4], lrow[4];
#pragma unroll
    for (int r = 0; r < 4; ++r) { mrow[r] = -1e30f; lrow[r] = 0.f; }

    // V staging mapping: t = tid>>2 (0..63), dblk = tid&3 (16 d's each)
    int vt = tid >> 2, vdb = tid & 3;
    // P region base (u16 idx)
    int pbase = 8704 + wave * 1088;

    for (int ch = 0; ch < 13; ++ch) {
        int tc = ch * 64;
        int vb = (ch & 1) * 4352;
        // ---- stage V chunk transposed: V_lds[d][t] = V[tc+t][d]
        {
            int tg = tc + vt; if (tg > S_ - 1) tg = S_ - 1;
            const u16* src = vp + (size_t)tg * C_ + vdb * 16;
            bf16x8 r0 = *(const bf16x8*)src;
            bf16x8 r1 = *(const bf16x8*)(src + 8);
#pragma unroll
            for (int e = 0; e < 8; ++e) {
                sm[vb + (vdb * 16 + e) * 68 + vt]       = (u16)r0[e];
                sm[vb + (vdb * 16 + 8 + e) * 68 + vt]   = (u16)r1[e];
            }
        }
        __syncthreads();

        // ---- QK^T: 4 t-tiles of 16
        f32x4 s[4];
#pragma unroll
        for (int tt = 0; tt < 4; ++tt) {
            int tg = tc + tt * 16 + lq; if (tg > S_ - 1) tg = S_ - 1;
            const u16* kptr = kp + (size_t)tg * C_ + quad * 8;
            bf16x8 bk0 = *(const bf16x8*)kptr;
            bf16x8 bk1 = *(const bf16x8*)(kptr + 32);
            f32x4 acc = {0.f,0.f,0.f,0.f};
            acc = __builtin_amdgcn_mfma_f32_16x16x32_bf16(aq0, bk0, acc, 0, 0, 0);
            acc = __builtin_amdgcn_mfma_f32_16x16x32_bf16(aq1, bk1, acc, 0, 0, 0);
#pragma unroll
            for (int r = 0; r < 4; ++r) acc[r] *= SCALE_;
            if (tc + tt * 16 >= S_) {
#pragma unroll
                for (int r = 0; r < 4; ++r) acc[r] = -1e30f;
            }
            s[tt] = acc;
        }
        // ---- online softmax (rows = (quad)*4 + r, 16 lanes per row group)
        float mc[4], al[4], rs[4];
#pragma unroll
        for (int r = 0; r < 4; ++r)
            mc[r] = fmaxf(fmaxf(s[0][r], s[1][r]), fmaxf(s[2][r], s[3][r]));
#pragma unroll
        for (int msk = 1; msk <= 8; msk <<= 1)
#pragma unroll
            for (int r = 0; r < 4; ++r)
                mc[r] = fmaxf(mc[r], __shfl_xor(mc[r], msk));
#pragma unroll
        for (int r = 0; r < 4; ++r) {
            float mn = fmaxf(mrow[r], mc[r]);
            al[r] = __expf(mrow[r] - mn);
            mrow[r] = mn;
            rs[r] = 0.f;
        }
        // p = exp(s - m), round to bf16 (consistency with PV numerator),
        // write to P_lds row-major [m=row][k=col], stride 68 u16
#pragma unroll
        for (int tt = 0; tt < 4; ++tt) {
#pragma unroll
            for (int r = 0; r < 4; ++r) {
                float p = __expf(s[tt][r] - mrow[r]);
                u16 pb = f2bf(p);
                sm[pbase + (quad * 4 + r) * 68 + tt * 16 + lq] = pb;
                rs[r] += bf2f(pb);
            }
        }
#pragma unroll
        for (int msk = 1; msk <= 8; msk <<= 1)
#pragma unroll
            for (int r = 0; r < 4; ++r)
                rs[r] += __shfl_xor(rs[r], msk);
#pragma unroll
        for (int r = 0; r < 4; ++r) lrow[r] = lrow[r] * al[r] + rs[r];
        __syncthreads();

        // ---- rescale O by alpha
#pragma unroll
        for (int r = 0; r < 4; ++r) {
            o0[r] *= al[r]; o1[r] *= al[r]; o2[r] *= al[r]; o3[r] *= al[r];
        }
        // ---- P A-frags from LDS (k = t-halves 0..31, 32..63)
        union { u64 q[2]; bf16x8 v; } ap0, ap1;
        {
            const char* base = (const char*)sm;
            int i0 = pbase + lq * 68 + quad * 8;
            ap0.q[0] = *(const u64*)(base + 2 * i0);
            ap0.q[1] = *(const u64*)(base + 2 * (i0 + 32));   // k+? no: +32 elems
            int i1 = i0 + 32;                                  // k base 32
            // NOTE: frag k-layout: elements j=0..7 at k=quad*8+j (+32 for frag2)
            ap0.q[1] = *(const u64*)(base + 2 * (i0 + 4));     // contiguous 8 bf16
            ap1.q[0] = *(const u64*)(base + 2 * i1);
            ap1.q[1] = *(const u64*)(base + 2 * (i1 + 4));
        }
        // ---- PV: 4 d-tiles x 2 t-halves
#pragma unroll
        for (int dt = 0; dt < 4; ++dt) {
            union { u64 q[2]; bf16x8 v; } bv0, bv1;
            const char* base = (const char*)sm;
            int d = lq + 16 * dt;
            int j0 = vb + d * 68 + quad * 8;
            bv0.q[0] = *(const u64*)(base + 2 * j0);
            bv0.q[1] = *(const u64*)(base + 2 * (j0 + 4));
            int j1 = j0 + 32;
            bv1.q[0] = *(const u64*)(base + 2 * j1);
            bv1.q[1] = *(const u64*)(base + 2 * (j1 + 4));
            f32x4* op = (dt == 0) ? &o0 : (dt == 1) ? &o1 : (dt == 2) ? &o2 : &o3;
            *op = __builtin_amdgcn_mfma_f32_16x16x32_bf16(ap0.v, bv0.v, *op, 0, 0, 0);
            *op = __builtin_amdgcn_mfma_f32_16x16x32_bf16(ap1.v, bv1.v, *op, 0, 0, 0);
        }
        // (next iteration's V staging writes the other buffer; barrier at
        // its end orders everything)
    }

    // ---- epilogue: O /= l, store f32. Rows = qbase + quad*4 + r, col = lq+16dt
    float inv[4];
#pragma unroll
    for (int r = 0; r < 4; ++r) inv[r] = 1.f / lrow[r];
    size_t obase = ((size_t)z * NH_ + h) * S_ * HD_;
#pragma unroll
    for (int r = 0; r < 4; ++r) {
        int qr = qbase + quad * 4 + r;
        if (qr >= S_) continue;
        float* dst = out + obase + (size_t)qr * HD_ + lq;
        dst[0]  = o0[r] * inv[r];
        dst[16] = o1[r] * inv[r];
        dst[32] = o2[r] * inv[r];
        dst[48] = o3[r] * inv[r];
    }
}

// ---------------------------------------------------------------------------
extern "C" void kernel_launch(void* const* d_in, const int* in_sizes, int n_in,
                              void* d_out, int out_size, void* d_ws, size_t ws_size,
                              hipStream_t stream) {
    (void)in_sizes; (void)n_in; (void)out_size; (void)ws_size;
    const float* x1    = (const float*)d_in[0];
    const float* x2    = (const float*)d_in[3];
    const float* dw    = (const float*)d_in[6];
    const float* gamma = (const float*)d_in[7];
    const float* beta  = (const float*)d_in[8];
    const float* pw    = (const float*)d_in[9];
    const float* pwb   = (const float*)d_in[10];
    const float* lin   = (const float*)d_in[11];
    float* out = (float*)d_out;

    char* ws = (char*)d_ws;
    u16*  img = (u16*)(ws);
    u16*  y   = (u16*)(ws + 28901376);
    u16*  qkv = (u16*)(ws + 115605504);
    float* Wc = (float*)(ws + 202309632);
    float* Bc = (float*)(ws + 207618048);
    float* aS = (float*)(ws + 207631872);
    float* bS = (float*)(ws + 207645696);

    k_img  <<<dim3(25, 12, 48), dim3(32, 8), 0, stream>>>(x1, x2, img);
    k_conv <<<dim3(384, 16, 9), 256, 0, stream>>>(img, dw, y);
    k_stats<<<dim3(384, 9), 256, 0, stream>>>(y, gamma, beta, aS, bS);
    k_wcomb<<<dim3(48, 9), 384, 0, stream>>>(pw, pwb, lin, aS, bS, Wc, Bc);
    k_gemm <<<dim3(13, 6, 144), 256, 0, stream>>>(y, Wc, Bc, qkv);
    k_attn <<<dim3(13, 6, 48), 256, 0, stream>>>(qkv, out);
}

// Round 4
// 688.192 us; speedup vs baseline: 4.6604x; 1.4414x over previous
//
#include <hip/hip_runtime.h>

typedef unsigned short u16;
typedef unsigned int u32;
typedef unsigned long long u64;

#define B_   16
#define C_   384
#define H_   28
#define W_   28
#define S_   784
#define NH_  6
#define HD_  64
#define BS_  (B_ * S_)            // 12544
#define SCALE_ 0.05103103630798288f  // 384^-0.5
#define EPS_ 1e-5f

typedef __attribute__((ext_vector_type(8))) short bf16x8;
typedef __attribute__((ext_vector_type(4))) float f32x4;

__device__ __forceinline__ float bf2f(u16 u) {
    return __uint_as_float(((u32)u) << 16);
}
__device__ __forceinline__ float bflo(u32 u) { return __uint_as_float(u << 16); }
__device__ __forceinline__ float bfhi(u32 u) { return __uint_as_float(u & 0xffff0000u); }
__device__ __forceinline__ u16 f2bf(float f) {
    u32 x = __float_as_uint(f);
    u32 r = (x + 0x7fffu + ((x >> 16) & 1u)) >> 16;   // RNE
    return (u16)r;
}

// ---------------------------------------------------------------------------
// Kernel 1: img[3][b][s][c] (channel-last, bf16) — pure elementwise now.
// img0 = bf16(x1), img1 = bf16(x2), img2 = bf16(x1+x2)
// ---------------------------------------------------------------------------
#define IMG_ELEMS (B_ * S_ * C_)   // 4,816,896 per image
__global__ void k_img(const float* __restrict__ x1, const float* __restrict__ x2,
                      u16* __restrict__ img) {
    int i = blockIdx.y;
    size_t e = ((size_t)blockIdx.x * 256 + threadIdx.x) * 8;
    const float4* p1 = (const float4*)(x1 + e);
    const float4* p2 = (const float4*)(x2 + e);
    float v[8];
    if (i == 0) {
        float4 a = p1[0], b = p1[1];
        v[0]=a.x; v[1]=a.y; v[2]=a.z; v[3]=a.w; v[4]=b.x; v[5]=b.y; v[6]=b.z; v[7]=b.w;
    } else if (i == 1) {
        float4 a = p2[0], b = p2[1];
        v[0]=a.x; v[1]=a.y; v[2]=a.z; v[3]=a.w; v[4]=b.x; v[5]=b.y; v[6]=b.z; v[7]=b.w;
    } else {
        float4 a = p1[0], b = p1[1], c = p2[0], d = p2[1];
        v[0]=a.x+c.x; v[1]=a.y+c.y; v[2]=a.z+c.z; v[3]=a.w+c.w;
        v[4]=b.x+d.x; v[5]=b.y+d.y; v[6]=b.z+d.z; v[7]=b.w+d.w;
    }
    u16 o[8];
#pragma unroll
    for (int k = 0; k < 8; ++k) o[k] = f2bf(v[k]);
    *(uint4*)(img + (size_t)i * IMG_ELEMS + e) = *(uint4*)o;
}

// ---------------------------------------------------------------------------
// Kernel 2: depthwise 3x3 conv, channel-last. y[idx][b][s][c].
// Block = (h, b, idx), 384 threads (c = tid). Sliding window in registers.
// ---------------------------------------------------------------------------
__global__ void k_conv(const u16* __restrict__ img, const float* __restrict__ dw,
                       u16* __restrict__ y) {
    int c = threadIdx.x;            // 0..383
    int h = blockIdx.x;             // 0..27
    int b = blockIdx.y;
    int idx = blockIdx.z;
    int br = idx / 3;
    const u16* base = img + ((size_t)(br * B_ + b) * S_) * C_ + c;
    float wt[9];
#pragma unroll
    for (int t = 0; t < 9; ++t) wt[t] = dw[(idx * C_ + c) * 9 + t];
    float a[3][3];
#pragma unroll
    for (int dh = 0; dh < 3; ++dh) {
        int hh = h + dh - 1;
        bool hv = (hh >= 0) && (hh < H_);
        a[dh][0] = 0.f;
        a[dh][1] = hv ? bf2f(base[(hh * W_ + 0) * C_]) : 0.f;
        a[dh][2] = hv ? bf2f(base[(hh * W_ + 1) * C_]) : 0.f;
    }
    u16* dst = y + ((size_t)(idx * B_ + b) * S_ + h * W_) * C_ + c;
    for (int w = 0; w < W_; ++w) {
        float acc = a[0][0]*wt[0] + a[0][1]*wt[1] + a[0][2]*wt[2]
                  + a[1][0]*wt[3] + a[1][1]*wt[4] + a[1][2]*wt[5]
                  + a[2][0]*wt[6] + a[2][1]*wt[7] + a[2][2]*wt[8];
        dst[w * C_] = f2bf(acc);
        int wn = w + 2;
        bool wv = (wn < W_);
#pragma unroll
        for (int dh = 0; dh < 3; ++dh) {
            a[dh][0] = a[dh][1];
            a[dh][1] = a[dh][2];
            int hh = h + dh - 1;
            a[dh][2] = (wv && hh >= 0 && hh < H_) ? bf2f(base[(hh * W_ + wn) * C_]) : 0.f;
        }
    }
}

// ---------------------------------------------------------------------------
// Kernel 3a: BN partial sums per (idx, s-chunk, c). 384 thr, grid (49, 9).
// ---------------------------------------------------------------------------
__global__ void k_stats1(const u16* __restrict__ y, float* __restrict__ part) {
    int c = threadIdx.x;
    int sc = blockIdx.x;            // 0..48 (16 s each)
    int idx = blockIdx.y;
    float s = 0.f, q = 0.f;
    const u16* p = y + (size_t)idx * B_ * S_ * C_ + c;
    for (int b = 0; b < B_; ++b) {
        const u16* pb = p + (size_t)b * S_ * C_ + (size_t)sc * 16 * C_;
        for (int e = 0; e < 16; ++e) {
            float v = bf2f(pb[e * C_]);
            s += v; q += v * v;
        }
    }
    float* d = part + ((size_t)(idx * 49 + sc) * C_ + c) * 2;
    d[0] = s; d[1] = q;
}

// Kernel 3b: finalize folded affine. grid (9), 384 thr.
__global__ void k_stats2(const float* __restrict__ part,
                         const float* __restrict__ gamma, const float* __restrict__ beta,
                         float* __restrict__ aScale, float* __restrict__ bShift) {
    int c = threadIdx.x;
    int idx = blockIdx.x;
    float s = 0.f, q = 0.f;
    for (int sc = 0; sc < 49; ++sc) {
        const float* d = part + ((size_t)(idx * 49 + sc) * C_ + c) * 2;
        s += d[0]; q += d[1];
    }
    float mean = s / (float)BS_;
    float var  = q / (float)BS_ - mean * mean;
    float a = gamma[idx * C_ + c] * rsqrtf(var + EPS_);
    aScale[idx * C_ + c] = a;
    bShift[idx * C_ + c] = beta[idx * C_ + c] - mean * a;
}

// ---------------------------------------------------------------------------
// Kernel 4: combined weights. Wcb (bf16) [idx][o][c] = lin@pw * aScale[c];
// Bc[idx][o] = (lin@pw)@bShift + lin@pwb. All-f32 math, bf16 store.
// ---------------------------------------------------------------------------
__global__ void k_wcomb(const float* __restrict__ pw, const float* __restrict__ pwb,
                        const float* __restrict__ lin,
                        const float* __restrict__ aScale, const float* __restrict__ bShift,
                        u16* __restrict__ Wcb, float* __restrict__ Bc) {
    __shared__ float red[C_];
    int og = blockIdx.x;            // 0..47
    int idx = blockIdx.y;           // 0..8
    int c = threadIdx.x;            // 0..383
    int li = (idx < 3) ? idx : 3 + (idx % 3);   // replicate branch-2 lin reuse bug
    float acc[8];
#pragma unroll
    for (int k = 0; k < 8; ++k) acc[k] = 0.f;
    const float* pwm = pw + (idx * C_) * C_ + c;
    const float* lb  = lin + ((li * C_) + og * 8) * C_;
    for (int m = 0; m < C_; ++m) {
        float pv = pwm[m * C_];
#pragma unroll
        for (int k = 0; k < 8; ++k)
            acc[k] += lb[k * C_ + m] * pv;
    }
    float aS = aScale[idx * C_ + c];
    float bS = bShift[idx * C_ + c];
    float pwbc = pwb[idx * C_ + c];
    for (int k = 0; k < 8; ++k) {
        int o = og * 8 + k;
        Wcb[(idx * C_ + o) * C_ + c] = f2bf(acc[k] * aS);
        float part = acc[k] * bS + lin[(li * C_ + o) * C_ + c] * pwbc;
        red[c] = part;
        __syncthreads();
        if (c < 128) red[c] += red[c + 256];
        __syncthreads();
        if (c < 128) red[c] += red[c + 128];
        __syncthreads();
        for (int st = 64; st > 0; st >>= 1) {
            if (c < st) red[c] += red[c + st];
            __syncthreads();
        }
        if (c == 0) Bc[idx * C_ + o] = red[0];
        __syncthreads();
    }
}

// ---------------------------------------------------------------------------
// Kernel 5: MFMA GEMM, zero LDS (attention-QK pattern).
// qkv[idx][b][s][o] = sum_c y[idx][b][s][c] * Wcb[idx][o][c] + Bc[idx][o]
// Block 4 waves = 128s x 128o tile (wave = 64x64). Grid (7, 3, 144).
// A-frag: lane holds y[s_base+mt*16+(lane&15)][k=quad*8+j]  (16B contiguous)
// B-frag: lane holds Wcb[o_base+nt*16+(lane&15)][k=quad*8+j] (16B contiguous)
// C/D:    lane holds D[row=quad*4+r][col=lane&15]
// ---------------------------------------------------------------------------
__launch_bounds__(256)
__global__ void k_gemm(const u16* __restrict__ y, const u16* __restrict__ Wcb,
                       const float* __restrict__ Bc, u16* __restrict__ qkv) {
    int z = blockIdx.z;
    int idx = z >> 4, b = z & 15;
    int tid = threadIdx.x;
    int wave = tid >> 6;
    int lane = tid & 63;
    int lq = lane & 15;
    int quad = lane >> 4;
    int s_base = blockIdx.x * 128 + (wave >> 1) * 64;
    int o_base = blockIdx.y * 128 + (wave & 1) * 64;

    const u16* ybase = y + ((size_t)(idx * B_ + b) * S_) * C_;
    const u16* wbase = Wcb + (size_t)idx * C_ * C_;

    f32x4 acc[4][4];
#pragma unroll
    for (int i = 0; i < 4; ++i)
#pragma unroll
        for (int j = 0; j < 4; ++j) acc[i][j] = (f32x4){0.f,0.f,0.f,0.f};

    // precompute row pointers (clamped)
    const u16* arow[4];
    const u16* brow[4];
#pragma unroll
    for (int mt = 0; mt < 4; ++mt) {
        int s = s_base + mt * 16 + lq; if (s > S_ - 1) s = S_ - 1;
        arow[mt] = ybase + (size_t)s * C_;
    }
#pragma unroll
    for (int nt = 0; nt < 4; ++nt) {
        int o = o_base + nt * 16 + lq;
        brow[nt] = wbase + (size_t)o * C_;
    }

    for (int ks = 0; ks < 12; ++ks) {
        int ko = ks * 32 + quad * 8;
        bf16x8 af[4], bf[4];
#pragma unroll
        for (int mt = 0; mt < 4; ++mt) af[mt] = *(const bf16x8*)(arow[mt] + ko);
#pragma unroll
        for (int nt = 0; nt < 4; ++nt) bf[nt] = *(const bf16x8*)(brow[nt] + ko);
#pragma unroll
        for (int mt = 0; mt < 4; ++mt)
#pragma unroll
            for (int nt = 0; nt < 4; ++nt)
                acc[mt][nt] = __builtin_amdgcn_mfma_f32_16x16x32_bf16(
                    af[mt], bf[nt], acc[mt][nt], 0, 0, 0);
    }

    float bias[4];
#pragma unroll
    for (int nt = 0; nt < 4; ++nt) bias[nt] = Bc[idx * C_ + o_base + nt * 16 + lq];
    u16* obase = qkv + ((size_t)(idx * B_ + b) * S_) * C_;
#pragma unroll
    for (int mt = 0; mt < 4; ++mt) {
#pragma unroll
        for (int r = 0; r < 4; ++r) {
            int s = s_base + mt * 16 + quad * 4 + r;
            if (s >= S_) continue;
            u16* row = obase + (size_t)s * C_ + o_base + lq;
#pragma unroll
            for (int nt = 0; nt < 4; ++nt)
                row[nt * 16] = f2bf(acc[mt][nt][r] + bias[nt]);
        }
    }
}

// ---------------------------------------------------------------------------
// Kernel 6: MFMA flash attention (unchanged from round 3, dead line removed).
// ---------------------------------------------------------------------------
__launch_bounds__(256)
__global__ void k_attn(const u16* __restrict__ qkv, float* __restrict__ out) {
    __shared__ u16 sm[13056];

    int h = blockIdx.y;
    int z = blockIdx.z;             // br*16 + b
    int br = z >> 4;
    int qtile = blockIdx.x;         // 0..12
    int tid = threadIdx.x;
    int wave = tid >> 6;
    int lane = tid & 63;
    int lq = lane & 15;
    int quad = lane >> 4;

    int idxq = 3 * br;
    const u16* qp = qkv + (size_t)((idxq * B_ + (z & 15)) * S_) * C_ + h * HD_;
    const u16* kp = qkv + (size_t)(((idxq + 1) * B_ + (z & 15)) * S_) * C_ + h * HD_;
    const u16* vp = qkv + (size_t)(((idxq + 2) * B_ + (z & 15)) * S_) * C_ + h * HD_;

    int qbase = qtile * 64 + wave * 16;
    int qrow = qbase + lq; if (qrow > S_ - 1) qrow = S_ - 1;
    const u16* qptr = qp + (size_t)qrow * C_ + quad * 8;
    bf16x8 aq0 = *(const bf16x8*)qptr;
    bf16x8 aq1 = *(const bf16x8*)(qptr + 32);

    f32x4 o0 = {0.f,0.f,0.f,0.f}, o1 = o0, o2 = o0, o3 = o0;
    float mrow[4], lrow[4];
#pragma unroll
    for (int r = 0; r < 4; ++r) { mrow[r] = -1e30f; lrow[r] = 0.f; }

    int vt = tid >> 2, vdb = tid & 3;
    int pbase = 8704 + wave * 1088;

    for (int ch = 0; ch < 13; ++ch) {
        int tc = ch * 64;
        int vb = (ch & 1) * 4352;
        {
            int tg = tc + vt; if (tg > S_ - 1) tg = S_ - 1;
            const u16* src = vp + (size_t)tg * C_ + vdb * 16;
            bf16x8 r0 = *(const bf16x8*)src;
            bf16x8 r1 = *(const bf16x8*)(src + 8);
#pragma unroll
            for (int e = 0; e < 8; ++e) {
                sm[vb + (vdb * 16 + e) * 68 + vt]       = (u16)r0[e];
                sm[vb + (vdb * 16 + 8 + e) * 68 + vt]   = (u16)r1[e];
            }
        }
        __syncthreads();

        f32x4 s[4];
#pragma unroll
        for (int tt = 0; tt < 4; ++tt) {
            int tg = tc + tt * 16 + lq; if (tg > S_ - 1) tg = S_ - 1;
            const u16* kptr = kp + (size_t)tg * C_ + quad * 8;
            bf16x8 bk0 = *(const bf16x8*)kptr;
            bf16x8 bk1 = *(const bf16x8*)(kptr + 32);
            f32x4 acc = {0.f,0.f,0.f,0.f};
            acc = __builtin_amdgcn_mfma_f32_16x16x32_bf16(aq0, bk0, acc, 0, 0, 0);
            acc = __builtin_amdgcn_mfma_f32_16x16x32_bf16(aq1, bk1, acc, 0, 0, 0);
#pragma unroll
            for (int r = 0; r < 4; ++r) acc[r] *= SCALE_;
            if (tc + tt * 16 >= S_) {
#pragma unroll
                for (int r = 0; r < 4; ++r) acc[r] = -1e30f;
            }
            s[tt] = acc;
        }
        float mc[4], al[4], rs[4];
#pragma unroll
        for (int r = 0; r < 4; ++r)
            mc[r] = fmaxf(fmaxf(s[0][r], s[1][r]), fmaxf(s[2][r], s[3][r]));
#pragma unroll
        for (int msk = 1; msk <= 8; msk <<= 1)
#pragma unroll
            for (int r = 0; r < 4; ++r)
                mc[r] = fmaxf(mc[r], __shfl_xor(mc[r], msk));
#pragma unroll
        for (int r = 0; r < 4; ++r) {
            float mn = fmaxf(mrow[r], mc[r]);
            al[r] = __expf(mrow[r] - mn);
            mrow[r] = mn;
            rs[r] = 0.f;
        }
#pragma unroll
        for (int tt = 0; tt < 4; ++tt) {
#pragma unroll
            for (int r = 0; r < 4; ++r) {
                float p = __expf(s[tt][r] - mrow[r]);
                u16 pb = f2bf(p);
                sm[pbase + (quad * 4 + r) * 68 + tt * 16 + lq] = pb;
                rs[r] += bf2f(pb);
            }
        }
#pragma unroll
        for (int msk = 1; msk <= 8; msk <<= 1)
#pragma unroll
            for (int r = 0; r < 4; ++r)
                rs[r] += __shfl_xor(rs[r], msk);
#pragma unroll
        for (int r = 0; r < 4; ++r) lrow[r] = lrow[r] * al[r] + rs[r];
        __syncthreads();

#pragma unroll
        for (int r = 0; r < 4; ++r) {
            o0[r] *= al[r]; o1[r] *= al[r]; o2[r] *= al[r]; o3[r] *= al[r];
        }
        union { u64 q[2]; bf16x8 v; } ap0, ap1;
        {
            const char* base = (const char*)sm;
            int i0 = pbase + lq * 68 + quad * 8;
            int i1 = i0 + 32;
            ap0.q[0] = *(const u64*)(base + 2 * i0);
            ap0.q[1] = *(const u64*)(base + 2 * (i0 + 4));
            ap1.q[0] = *(const u64*)(base + 2 * i1);
            ap1.q[1] = *(const u64*)(base + 2 * (i1 + 4));
        }
#pragma unroll
        for (int dt = 0; dt < 4; ++dt) {
            union { u64 q[2]; bf16x8 v; } bv0, bv1;
            const char* base = (const char*)sm;
            int d = lq + 16 * dt;
            int j0 = vb + d * 68 + quad * 8;
            bv0.q[0] = *(const u64*)(base + 2 * j0);
            bv0.q[1] = *(const u64*)(base + 2 * (j0 + 4));
            int j1 = j0 + 32;
            bv1.q[0] = *(const u64*)(base + 2 * j1);
            bv1.q[1] = *(const u64*)(base + 2 * (j1 + 4));
            f32x4* op = (dt == 0) ? &o0 : (dt == 1) ? &o1 : (dt == 2) ? &o2 : &o3;
            *op = __builtin_amdgcn_mfma_f32_16x16x32_bf16(ap0.v, bv0.v, *op, 0, 0, 0);
            *op = __builtin_amdgcn_mfma_f32_16x16x32_bf16(ap1.v, bv1.v, *op, 0, 0, 0);
        }
    }

    float inv[4];
#pragma unroll
    for (int r = 0; r < 4; ++r) inv[r] = 1.f / lrow[r];
    size_t obase = ((size_t)z * NH_ + h) * S_ * HD_;
#pragma unroll
    for (int r = 0; r < 4; ++r) {
        int qr = qbase + quad * 4 + r;
        if (qr >= S_) continue;
        float* dst = out + obase + (size_t)qr * HD_ + lq;
        dst[0]  = o0[r] * inv[r];
        dst[16] = o1[r] * inv[r];
        dst[32] = o2[r] * inv[r];
        dst[48] = o3[r] * inv[r];
    }
}

// ---------------------------------------------------------------------------
extern "C" void kernel_launch(void* const* d_in, const int* in_sizes, int n_in,
                              void* d_out, int out_size, void* d_ws, size_t ws_size,
                              hipStream_t stream) {
    (void)in_sizes; (void)n_in; (void)out_size; (void)ws_size;
    const float* x1    = (const float*)d_in[0];
    const float* x2    = (const float*)d_in[3];
    const float* dw    = (const float*)d_in[6];
    const float* gamma = (const float*)d_in[7];
    const float* beta  = (const float*)d_in[8];
    const float* pw    = (const float*)d_in[9];
    const float* pwb   = (const float*)d_in[10];
    const float* lin   = (const float*)d_in[11];
    float* out = (float*)d_out;

    char* ws = (char*)d_ws;
    // ws layout (bytes):
    // img  bf16 [3][16][784][384]  @ 0          size 28,901,376
    // y    bf16 [9][16][784][384]  @ 28901376   size 86,704,128
    // qkv  bf16 [9][16][784][384]  @ 115605504  size 86,704,128
    // Wcb  bf16 [9][384][384]      @ 202309632  size 2,654,208
    // Bc   f32  [9][384]           @ 204963840  size 13,824
    // aS   f32  [9][384]           @ 204977664  size 13,824
    // bS   f32  [9][384]           @ 204991488  size 13,824
    // part f32  [9][49][384][2]    @ 205005312  size 1,354,752
    u16*  img = (u16*)(ws);
    u16*  y   = (u16*)(ws + 28901376);
    u16*  qkv = (u16*)(ws + 115605504);
    u16*  Wcb = (u16*)(ws + 202309632);
    float* Bc = (float*)(ws + 204963840);
    float* aS = (float*)(ws + 204977664);
    float* bS = (float*)(ws + 204991488);
    float* part = (float*)(ws + 205005312);

    k_img   <<<dim3(2352, 3), 256, 0, stream>>>(x1, x2, img);
    k_conv  <<<dim3(28, 16, 9), 384, 0, stream>>>(img, dw, y);
    k_stats1<<<dim3(49, 9), 384, 0, stream>>>(y, part);
    k_stats2<<<dim3(9), 384, 0, stream>>>(part, gamma, beta, aS, bS);
    k_wcomb <<<dim3(48, 9), 384, 0, stream>>>(pw, pwb, lin, aS, bS, Wcb, Bc);
    k_gemm  <<<dim3(7, 3, 144), 256, 0, stream>>>(y, Wcb, Bc, qkv);
    k_attn  <<<dim3(13, 6, 48), 256, 0, stream>>>(qkv, out);
}

// Round 5
// 684.733 us; speedup vs baseline: 4.6840x; 1.0051x over previous
//
#include <hip/hip_runtime.h>

typedef unsigned short u16;
typedef unsigned int u32;
typedef unsigned long long u64;

#define B_   16
#define C_   384
#define H_   28
#define W_   28
#define S_   784
#define NH_  6
#define HD_  64
#define BS_  (B_ * S_)            // 12544
#define SCALE_ 0.05103103630798288f  // 384^-0.5
#define EPS_ 1e-5f

typedef __attribute__((ext_vector_type(8))) short bf16x8;
typedef __attribute__((ext_vector_type(4))) float f32x4;

__device__ __forceinline__ float bf2f(u16 u) {
    return __uint_as_float(((u32)u) << 16);
}
__device__ __forceinline__ u16 f2bf(float f) {
    u32 x = __float_as_uint(f);
    u32 r = (x + 0x7fffu + ((x >> 16) & 1u)) >> 16;   // RNE
    return (u16)r;
}

// ---------------------------------------------------------------------------
// Kernel 1: img[3][b][s][c] (channel-last, bf16) — pure elementwise.
// ---------------------------------------------------------------------------
#define IMG_ELEMS (B_ * S_ * C_)   // 4,816,896 per image
__global__ void k_img(const float* __restrict__ x1, const float* __restrict__ x2,
                      u16* __restrict__ img) {
    int i = blockIdx.y;
    size_t e = ((size_t)blockIdx.x * 256 + threadIdx.x) * 8;
    const float4* p1 = (const float4*)(x1 + e);
    const float4* p2 = (const float4*)(x2 + e);
    float v[8];
    if (i == 0) {
        float4 a = p1[0], b = p1[1];
        v[0]=a.x; v[1]=a.y; v[2]=a.z; v[3]=a.w; v[4]=b.x; v[5]=b.y; v[6]=b.z; v[7]=b.w;
    } else if (i == 1) {
        float4 a = p2[0], b = p2[1];
        v[0]=a.x; v[1]=a.y; v[2]=a.z; v[3]=a.w; v[4]=b.x; v[5]=b.y; v[6]=b.z; v[7]=b.w;
    } else {
        float4 a = p1[0], b = p1[1], c = p2[0], d = p2[1];
        v[0]=a.x+c.x; v[1]=a.y+c.y; v[2]=a.z+c.z; v[3]=a.w+c.w;
        v[4]=b.x+d.x; v[5]=b.y+d.y; v[6]=b.z+d.z; v[7]=b.w+d.w;
    }
    u16 o[8];
#pragma unroll
    for (int k = 0; k < 8; ++k) o[k] = f2bf(v[k]);
    *(uint4*)(img + (size_t)i * IMG_ELEMS + e) = *(uint4*)o;
}

// ---------------------------------------------------------------------------
// Kernel 2: depthwise 3x3 conv, channel-last. y[idx][b][s][c].
// ---------------------------------------------------------------------------
__global__ void k_conv(const u16* __restrict__ img, const float* __restrict__ dw,
                       u16* __restrict__ y) {
    int c = threadIdx.x;            // 0..383
    int h = blockIdx.x;             // 0..27
    int b = blockIdx.y;
    int idx = blockIdx.z;
    int br = idx / 3;
    const u16* base = img + ((size_t)(br * B_ + b) * S_) * C_ + c;
    float wt[9];
#pragma unroll
    for (int t = 0; t < 9; ++t) wt[t] = dw[(idx * C_ + c) * 9 + t];
    float a[3][3];
#pragma unroll
    for (int dh = 0; dh < 3; ++dh) {
        int hh = h + dh - 1;
        bool hv = (hh >= 0) && (hh < H_);
        a[dh][0] = 0.f;
        a[dh][1] = hv ? bf2f(base[(hh * W_ + 0) * C_]) : 0.f;
        a[dh][2] = hv ? bf2f(base[(hh * W_ + 1) * C_]) : 0.f;
    }
    u16* dst = y + ((size_t)(idx * B_ + b) * S_ + h * W_) * C_ + c;
    for (int w = 0; w < W_; ++w) {
        float acc = a[0][0]*wt[0] + a[0][1]*wt[1] + a[0][2]*wt[2]
                  + a[1][0]*wt[3] + a[1][1]*wt[4] + a[1][2]*wt[5]
                  + a[2][0]*wt[6] + a[2][1]*wt[7] + a[2][2]*wt[8];
        dst[w * C_] = f2bf(acc);
        int wn = w + 2;
        bool wv = (wn < W_);
#pragma unroll
        for (int dh = 0; dh < 3; ++dh) {
            a[dh][0] = a[dh][1];
            a[dh][1] = a[dh][2];
            int hh = h + dh - 1;
            a[dh][2] = (wv && hh >= 0 && hh < H_) ? bf2f(base[(hh * W_ + wn) * C_]) : 0.f;
        }
    }
}

// ---------------------------------------------------------------------------
// Kernel 3a: BN partial sums per (idx, s-chunk, c). 384 thr, grid (49, 9).
// ---------------------------------------------------------------------------
__global__ void k_stats1(const u16* __restrict__ y, float* __restrict__ part) {
    int c = threadIdx.x;
    int sc = blockIdx.x;            // 0..48 (16 s each)
    int idx = blockIdx.y;
    float s = 0.f, q = 0.f;
    const u16* p = y + (size_t)idx * B_ * S_ * C_ + c;
    for (int b = 0; b < B_; ++b) {
        const u16* pb = p + (size_t)b * S_ * C_ + (size_t)sc * 16 * C_;
        for (int e = 0; e < 16; ++e) {
            float v = bf2f(pb[e * C_]);
            s += v; q += v * v;
        }
    }
    float* d = part + ((size_t)(idx * 49 + sc) * C_ + c) * 2;
    d[0] = s; d[1] = q;
}

// Kernel 3b: finalize folded affine. grid (9), 384 thr.
__global__ void k_stats2(const float* __restrict__ part,
                         const float* __restrict__ gamma, const float* __restrict__ beta,
                         float* __restrict__ aScale, float* __restrict__ bShift) {
    int c = threadIdx.x;
    int idx = blockIdx.x;
    float s = 0.f, q = 0.f;
    for (int sc = 0; sc < 49; ++sc) {
        const float* d = part + ((size_t)(idx * 49 + sc) * C_ + c) * 2;
        s += d[0]; q += d[1];
    }
    float mean = s / (float)BS_;
    float var  = q / (float)BS_ - mean * mean;
    float a = gamma[idx * C_ + c] * rsqrtf(var + EPS_);
    aScale[idx * C_ + c] = a;
    bShift[idx * C_ + c] = beta[idx * C_ + c] - mean * a;
}

// ---------------------------------------------------------------------------
// Kernel 4: combined weights. Wcb (bf16) [idx][o][c] = lin@pw * aScale[c];
// Bc[idx][o] = (lin@pw)@bShift + lin@pwb. Wave-shfl reduction (2 barriers/k).
// ---------------------------------------------------------------------------
__global__ void k_wcomb(const float* __restrict__ pw, const float* __restrict__ pwb,
                        const float* __restrict__ lin,
                        const float* __restrict__ aScale, const float* __restrict__ bShift,
                        u16* __restrict__ Wcb, float* __restrict__ Bc) {
    __shared__ float red[8];
    int og = blockIdx.x;            // 0..47
    int idx = blockIdx.y;           // 0..8
    int c = threadIdx.x;            // 0..383
    int wave = c >> 6, lane = c & 63;
    int li = (idx < 3) ? idx : 3 + (idx % 3);   // replicate branch-2 lin reuse bug
    float acc[8];
#pragma unroll
    for (int k = 0; k < 8; ++k) acc[k] = 0.f;
    const float* pwm = pw + (idx * C_) * C_ + c;
    const float* lb  = lin + ((li * C_) + og * 8) * C_;
    for (int m = 0; m < C_; ++m) {
        float pv = pwm[m * C_];
#pragma unroll
        for (int k = 0; k < 8; ++k)
            acc[k] += lb[k * C_ + m] * pv;
    }
    float aS = aScale[idx * C_ + c];
    float bS = bShift[idx * C_ + c];
    float pwbc = pwb[idx * C_ + c];
    for (int k = 0; k < 8; ++k) {
        int o = og * 8 + k;
        Wcb[(idx * C_ + o) * C_ + c] = f2bf(acc[k] * aS);
        float v = acc[k] * bS + lin[(li * C_ + o) * C_ + c] * pwbc;
#pragma unroll
        for (int msk = 1; msk < 64; msk <<= 1) v += __shfl_xor(v, msk);
        if (lane == 0) red[wave] = v;
        __syncthreads();
        if (c == 0)
            Bc[idx * C_ + o] = red[0] + red[1] + red[2] + red[3] + red[4] + red[5];
        __syncthreads();
    }
}

// ---------------------------------------------------------------------------
// Kernel 5: MFMA GEMM, zero LDS. (unchanged)
// ---------------------------------------------------------------------------
__launch_bounds__(256)
__global__ void k_gemm(const u16* __restrict__ y, const u16* __restrict__ Wcb,
                       const float* __restrict__ Bc, u16* __restrict__ qkv) {
    int z = blockIdx.z;
    int idx = z >> 4, b = z & 15;
    int tid = threadIdx.x;
    int wave = tid >> 6;
    int lane = tid & 63;
    int lq = lane & 15;
    int quad = lane >> 4;
    int s_base = blockIdx.x * 128 + (wave >> 1) * 64;
    int o_base = blockIdx.y * 128 + (wave & 1) * 64;

    const u16* ybase = y + ((size_t)(idx * B_ + b) * S_) * C_;
    const u16* wbase = Wcb + (size_t)idx * C_ * C_;

    f32x4 acc[4][4];
#pragma unroll
    for (int i = 0; i < 4; ++i)
#pragma unroll
        for (int j = 0; j < 4; ++j) acc[i][j] = (f32x4){0.f,0.f,0.f,0.f};

    const u16* arow[4];
    const u16* brow[4];
#pragma unroll
    for (int mt = 0; mt < 4; ++mt) {
        int s = s_base + mt * 16 + lq; if (s > S_ - 1) s = S_ - 1;
        arow[mt] = ybase + (size_t)s * C_;
    }
#pragma unroll
    for (int nt = 0; nt < 4; ++nt) {
        int o = o_base + nt * 16 + lq;
        brow[nt] = wbase + (size_t)o * C_;
    }

    for (int ks = 0; ks < 12; ++ks) {
        int ko = ks * 32 + quad * 8;
        bf16x8 af[4], bf[4];
#pragma unroll
        for (int mt = 0; mt < 4; ++mt) af[mt] = *(const bf16x8*)(arow[mt] + ko);
#pragma unroll
        for (int nt = 0; nt < 4; ++nt) bf[nt] = *(const bf16x8*)(brow[nt] + ko);
#pragma unroll
        for (int mt = 0; mt < 4; ++mt)
#pragma unroll
            for (int nt = 0; nt < 4; ++nt)
                acc[mt][nt] = __builtin_amdgcn_mfma_f32_16x16x32_bf16(
                    af[mt], bf[nt], acc[mt][nt], 0, 0, 0);
    }

    float bias[4];
#pragma unroll
    for (int nt = 0; nt < 4; ++nt) bias[nt] = Bc[idx * C_ + o_base + nt * 16 + lq];
    u16* obase = qkv + ((size_t)(idx * B_ + b) * S_) * C_;
#pragma unroll
    for (int mt = 0; mt < 4; ++mt) {
#pragma unroll
        for (int r = 0; r < 4; ++r) {
            int s = s_base + mt * 16 + quad * 4 + r;
            if (s >= S_) continue;
            u16* row = obase + (size_t)s * C_ + o_base + lq;
#pragma unroll
            for (int nt = 0; nt < 4; ++nt)
                row[nt * 16] = f2bf(acc[mt][nt][r] + bias[nt]);
        }
    }
}

// ---------------------------------------------------------------------------
// Kernel 6: MFMA flash attention, T=128 chunks.
// Block = 4 waves, one (br,b,h), 64 Q-rows (16/wave). 7 chunks of 128 t.
// LDS: V [d=64][t=128] stride 132 (single buffer, 2 barriers/chunk);
//      P per-wave [q=16][t=128] stride 132.
// SCALE folded into exp args (m tracked in raw-logit domain).
// V staged via packed ds_write_b64 (4 rows x 8 d per thread).
// p stored truncated-bf16; same value used in denominator (consistent).
// ---------------------------------------------------------------------------
__launch_bounds__(256)
__global__ void k_attn(const u16* __restrict__ qkv, float* __restrict__ out) {
    __shared__ u16 sm[16896];   // V: [0, 8448); P: 8448 + wave*2112

    int h = blockIdx.y;
    int z = blockIdx.z;             // br*16 + b
    int br = z >> 4;
    int qtile = blockIdx.x;         // 0..12
    int tid = threadIdx.x;
    int wave = tid >> 6;
    int lane = tid & 63;
    int lq = lane & 15;
    int quad = lane >> 4;

    int idxq = 3 * br;
    const u16* qp = qkv + (size_t)((idxq * B_ + (z & 15)) * S_) * C_ + h * HD_;
    const u16* kp = qkv + (size_t)(((idxq + 1) * B_ + (z & 15)) * S_) * C_ + h * HD_;
    const u16* vp = qkv + (size_t)(((idxq + 2) * B_ + (z & 15)) * S_) * C_ + h * HD_;

    int qbase = qtile * 64 + wave * 16;
    int qrow = qbase + lq; if (qrow > S_ - 1) qrow = S_ - 1;
    const u16* qptr = qp + (size_t)qrow * C_ + quad * 8;
    bf16x8 aq0 = *(const bf16x8*)qptr;
    bf16x8 aq1 = *(const bf16x8*)(qptr + 32);

    f32x4 o0 = {0.f,0.f,0.f,0.f}, o1 = o0, o2 = o0, o3 = o0;
    float mrow[4], lrow[4];
#pragma unroll
    for (int r = 0; r < 4; ++r) { mrow[r] = -1e30f; lrow[r] = 0.f; }

    // V staging mapping: 4 consecutive t, 8 d per thread
    int tg4 = (tid & 31) * 4;       // 0..124
    int dg  = (tid >> 5) * 8;       // 0..56
    int pbase = 8448 + wave * 2112;

    for (int ch = 0; ch < 7; ++ch) {
        int tc = ch * 128;
        // ---- load V rows (global, before barrier for latency overlap)
        bf16x8 vr[4];
#pragma unroll
        for (int i = 0; i < 4; ++i) {
            int tg = tc + tg4 + i; if (tg > S_ - 1) tg = S_ - 1;
            vr[i] = *(const bf16x8*)(vp + (size_t)tg * C_ + dg);
        }
        __syncthreads();            // prior chunk's PV reads complete
#pragma unroll
        for (int e = 0; e < 8; ++e) {
            u64 pk = (u64)(u16)vr[0][e] | ((u64)(u16)vr[1][e] << 16)
                   | ((u64)(u16)vr[2][e] << 32) | ((u64)(u16)vr[3][e] << 48);
            *(u64*)&sm[(dg + e) * 132 + tg4] = pk;
        }
        __syncthreads();            // V visible to all waves

        // ---- QK^T: 8 t-tiles of 16 (raw logits, scale folded into exp)
        f32x4 s[8];
#pragma unroll
        for (int tt = 0; tt < 8; ++tt) {
            int tg = tc + tt * 16 + lq; if (tg > S_ - 1) tg = S_ - 1;
            const u16* kptr = kp + (size_t)tg * C_ + quad * 8;
            bf16x8 bk0 = *(const bf16x8*)kptr;
            bf16x8 bk1 = *(const bf16x8*)(kptr + 32);
            f32x4 acc = {0.f,0.f,0.f,0.f};
            acc = __builtin_amdgcn_mfma_f32_16x16x32_bf16(aq0, bk0, acc, 0, 0, 0);
            acc = __builtin_amdgcn_mfma_f32_16x16x32_bf16(aq1, bk1, acc, 0, 0, 0);
            if (tc + tt * 16 >= S_) {
#pragma unroll
                for (int r = 0; r < 4; ++r) acc[r] = -1e30f;
            }
            s[tt] = acc;
        }
        // ---- online softmax (raw-domain max; exp scaled)
        float mc[4], al[4], rs[4];
#pragma unroll
        for (int r = 0; r < 4; ++r) {
            float m01 = fmaxf(s[0][r], s[1][r]), m23 = fmaxf(s[2][r], s[3][r]);
            float m45 = fmaxf(s[4][r], s[5][r]), m67 = fmaxf(s[6][r], s[7][r]);
            mc[r] = fmaxf(fmaxf(m01, m23), fmaxf(m45, m67));
        }
#pragma unroll
        for (int msk = 1; msk <= 8; msk <<= 1)
#pragma unroll
            for (int r = 0; r < 4; ++r)
                mc[r] = fmaxf(mc[r], __shfl_xor(mc[r], msk));
#pragma unroll
        for (int r = 0; r < 4; ++r) {
            float mn = fmaxf(mrow[r], mc[r]);
            al[r] = __expf((mrow[r] - mn) * SCALE_);
            mrow[r] = mn;
            rs[r] = 0.f;
        }
#pragma unroll
        for (int tt = 0; tt < 8; ++tt) {
#pragma unroll
            for (int r = 0; r < 4; ++r) {
                float p = __expf((s[tt][r] - mrow[r]) * SCALE_);
                u16 pb = (u16)(__float_as_uint(p) >> 16);   // trunc bf16
                sm[pbase + (quad * 4 + r) * 132 + tt * 16 + lq] = pb;
                rs[r] += __uint_as_float((u32)pb << 16);
            }
        }
#pragma unroll
        for (int msk = 1; msk <= 8; msk <<= 1)
#pragma unroll
            for (int r = 0; r < 4; ++r)
                rs[r] += __shfl_xor(rs[r], msk);
#pragma unroll
        for (int r = 0; r < 4; ++r) lrow[r] = lrow[r] * al[r] + rs[r];

        // ---- rescale O
#pragma unroll
        for (int r = 0; r < 4; ++r) {
            o0[r] *= al[r]; o1[r] *= al[r]; o2[r] *= al[r]; o3[r] *= al[r];
        }
        // ---- P A-frags (4 k-halves of 32); per-wave region, no barrier needed
        union { u64 q[2]; bf16x8 v; } ap[4];
        const char* bp = (const char*)sm;
        int i0 = pbase + lq * 132;
#pragma unroll
        for (int n = 0; n < 4; ++n) {
            int a = i0 + n * 32 + quad * 8;
            ap[n].q[0] = *(const u64*)(bp + 2 * a);
            ap[n].q[1] = *(const u64*)(bp + 2 * (a + 4));
        }
        // ---- PV: 4 d-tiles x 4 k-halves
#pragma unroll
        for (int dt = 0; dt < 4; ++dt) {
            f32x4* op = (dt == 0) ? &o0 : (dt == 1) ? &o1 : (dt == 2) ? &o2 : &o3;
#pragma unroll
            for (int kh = 0; kh < 4; ++kh) {
                union { u64 q[2]; bf16x8 v; } bv;
                int j = (dt * 16 + lq) * 132 + kh * 32 + quad * 8;
                bv.q[0] = *(const u64*)(bp + 2 * j);
                bv.q[1] = *(const u64*)(bp + 2 * (j + 4));
                *op = __builtin_amdgcn_mfma_f32_16x16x32_bf16(ap[kh].v, bv.v, *op, 0, 0, 0);
            }
        }
    }

    // ---- epilogue
    float inv[4];
#pragma unroll
    for (int r = 0; r < 4; ++r) inv[r] = 1.f / lrow[r];
    size_t obase = ((size_t)z * NH_ + h) * S_ * HD_;
#pragma unroll
    for (int r = 0; r < 4; ++r) {
        int qr = qbase + quad * 4 + r;
        if (qr >= S_) continue;
        float* dst = out + obase + (size_t)qr * HD_ + lq;
        dst[0]  = o0[r] * inv[r];
        dst[16] = o1[r] * inv[r];
        dst[32] = o2[r] * inv[r];
        dst[48] = o3[r] * inv[r];
    }
}

// ---------------------------------------------------------------------------
extern "C" void kernel_launch(void* const* d_in, const int* in_sizes, int n_in,
                              void* d_out, int out_size, void* d_ws, size_t ws_size,
                              hipStream_t stream) {
    (void)in_sizes; (void)n_in; (void)out_size; (void)ws_size;
    const float* x1    = (const float*)d_in[0];
    const float* x2    = (const float*)d_in[3];
    const float* dw    = (const float*)d_in[6];
    const float* gamma = (const float*)d_in[7];
    const float* beta  = (const float*)d_in[8];
    const float* pw    = (const float*)d_in[9];
    const float* pwb   = (const float*)d_in[10];
    const float* lin   = (const float*)d_in[11];
    float* out = (float*)d_out;

    char* ws = (char*)d_ws;
    u16*  img = (u16*)(ws);
    u16*  y   = (u16*)(ws + 28901376);
    u16*  qkv = (u16*)(ws + 115605504);
    u16*  Wcb = (u16*)(ws + 202309632);
    float* Bc = (float*)(ws + 204963840);
    float* aS = (float*)(ws + 204977664);
    float* bS = (float*)(ws + 204991488);
    float* part = (float*)(ws + 205005312);

    k_img   <<<dim3(2352, 3), 256, 0, stream>>>(x1, x2, img);
    k_conv  <<<dim3(28, 16, 9), 384, 0, stream>>>(img, dw, y);
    k_stats1<<<dim3(49, 9), 384, 0, stream>>>(y, part);
    k_stats2<<<dim3(9), 384, 0, stream>>>(part, gamma, beta, aS, bS);
    k_wcomb <<<dim3(48, 9), 384, 0, stream>>>(pw, pwb, lin, aS, bS, Wcb, Bc);
    k_gemm  <<<dim3(7, 3, 144), 256, 0, stream>>>(y, Wcb, Bc, qkv);
    k_attn  <<<dim3(13, 6, 48), 256, 0, stream>>>(qkv, out);
}